// Round 15
// baseline (322.385 us; speedup 1.0000x reference)
//
#include <hip/hip_runtime.h>
#include <hip/hip_bf16.h>
#include <math.h>

typedef __attribute__((ext_vector_type(8))) short short8;
typedef __attribute__((ext_vector_type(4))) float f32x4;
typedef __attribute__((ext_vector_type(2))) float f32x2;

#define INJ_LAM 0.8f
#define BSH 9
#define BWD 512     // nodes per bucket
#define BCAP 12288  // padded per-bucket edge capacity (avg 8163 + 45 sigma)

__device__ inline float bf2f(unsigned short s){
  union{unsigned u; float f;} v; v.u=((unsigned)s)<<16; return v.f;
}
__device__ inline unsigned short f2bf(float f){
  __hip_bfloat16 h=__float2bfloat16(f);
  return *reinterpret_cast<unsigned short*>(&h);
}
__device__ inline unsigned pack2(float lo, float hi){
  return ((unsigned)f2bf(hi)<<16)|(unsigned)f2bf(lo);
}

// prep: weight transpose/cast + pre-halved biases + zero flags/zcur
__global__ void k_prep(const float* __restrict__ W1,const float* __restrict__ Wl1,
                       const float* __restrict__ W2,const float* __restrict__ Wl2,
                       const float* __restrict__ Wm1,const float* __restrict__ Wm2,
                       const float* __restrict__ b1,const float* __restrict__ b2,
                       unsigned short* __restrict__ Wt1, unsigned short* __restrict__ Wt2,
                       unsigned short* __restrict__ Wm1t, unsigned short* __restrict__ Wm2tp,
                       float* __restrict__ bh1, float* __restrict__ bh2,
                       unsigned* __restrict__ flags32, int nf4,
                       unsigned* __restrict__ zcur8){
  int i=blockIdx.x*blockDim.x+threadIdx.x;
  if(i<256*128){
    int c=i>>7, k=i&127;
    float v1=(c<128)?W1[k*128+c]:Wl1[k*128+(c-128)];
    float v2=(c<128)?W2[k*128+c]:Wl2[k*128+(c-128)];
    Wt1[i]=f2bf(v1); Wt2[i]=f2bf(v2);
    if(c<128) Wm1t[i]=f2bf(Wm1[k*128+c]);
    if(c<16)  Wm2tp[i]=f2bf((c<10)?Wm2[k*10+c]:0.f);
    if(i<128){ bh1[i]=0.5f*b1[i]; bh2[i]=0.5f*b2[i]; }
  }
  if(i<nf4) flags32[i]=0u;
  if(i<2048) zcur8[i]=0u;
}

// bscatter: group edges by bucket into PADDED per-bucket arrays (b*BCAP).
__launch_bounds__(256)
__global__ void k_bscatter(const int* __restrict__ src, const int* __restrict__ dst,
                           unsigned* __restrict__ zcur8,
                           int* __restrict__ psrc, int* __restrict__ pdst, int E){
  __shared__ unsigned lh[256];
  __shared__ unsigned gb[256];
  int t=threadIdx.x;
  lh[t]=0u; __syncthreads();
  int base=blockIdx.x*2048;
  unsigned lr[8]; int bk[8], sv[8], dv_[8];
  #pragma unroll
  for(int k=0;k<8;k++){
    int e=base+k*256+t;
    if(e<E){
      int d=dst[e]; int b=d>>BSH;
      bk[k]=b; dv_[k]=d; sv[k]=src[e];
      lr[k]=atomicAdd(&lh[b],1u);
    } else bk[k]=-1;
  }
  __syncthreads();
  if(lh[t]) gb[t]=atomicAdd(&zcur8[t*8],lh[t]);
  __syncthreads();
  #pragma unroll
  for(int k=0;k<8;k++){
    if(bk[k]>=0){
      unsigned p=(unsigned)bk[k]*BCAP+gb[bk[k]]+lr[k];
      psrc[p]=sv[k]; pdst[p]=dv_[k];
    }
  }
}

// bucket: prefix over zcur8 counts -> csr bases; per-node cnt+rank via LDS
// atomics; LDS scan -> offs; compact csr. meta = start|(deg<<21); inject flags.
__launch_bounds__(256)
__global__ void k_bucket(const int* __restrict__ psrc, const int* __restrict__ pdst,
                         const unsigned* __restrict__ zcur8, unsigned* __restrict__ rank,
                         unsigned* __restrict__ meta, float* __restrict__ dinv,
                         int* __restrict__ csr,
                         const int* __restrict__ inj, unsigned char* __restrict__ flag,
                         int N, int NI, int NBK){
  __shared__ unsigned lc[BWD];
  __shared__ unsigned lo[BWD];
  __shared__ unsigned ss[256];
  int b=blockIdx.x, t=threadIdx.x;
  for(int i=b*256+t;i<NI;i+=gridDim.x*256) flag[inj[i]]=1;
  unsigned v=(t<NBK)?zcur8[t*8]:0u;
  ss[t]=v; lc[t]=0u; lc[t+256]=0u;
  __syncthreads();
  for(int off=1;off<256;off<<=1){
    unsigned u=(t>=off)?ss[t-off]:0u; __syncthreads();
    ss[t]+=u; __syncthreads();
  }
  unsigned cnt_b=zcur8[b*8];
  unsigned e1=ss[b];
  unsigned e0=e1-cnt_b;
  __syncthreads();
  int lo_node=b<<BSH;
  unsigned pbase=(unsigned)b*BCAP;
  for(unsigned i=t;i<cnt_b;i+=256){
    int dl=pdst[pbase+i]-lo_node;
    rank[pbase+i]=atomicAdd(&lc[dl],1u);
  }
  __syncthreads();
  unsigned c0=lc[2*t], c1=lc[2*t+1], ps=c0+c1;
  ss[t]=ps; __syncthreads();
  for(int off=1;off<256;off<<=1){
    unsigned u=(t>=off)?ss[t-off]:0u; __syncthreads();
    ss[t]+=u; __syncthreads();
  }
  unsigned excl=ss[t]-ps;
  lo[2*t]=excl; lo[2*t+1]=excl+c0;
  __syncthreads();
  #pragma unroll
  for(int k=0;k<2;k++){
    int nl=t+k*256; int node=lo_node+nl;
    if(node<N){
      unsigned c=lc[nl];
      meta[node]=(e0+lo[nl])|(c<<21);
      dinv[node]=rsqrtf((float)(c+1u));
    }
  }
  for(unsigned i=t;i<cnt_b;i+=256){
    int dl=pdst[pbase+i]-lo_node;
    csr[e0+lo[dl]+rank[pbase+i]]=psrc[pbase+i];
  }
}

template<bool FP32IN>
__device__ inline void load_afrag(const void* __restrict__ Xv, size_t arow, int l4, short8* a){
  if(FP32IN){
    const float* X=(const float*)Xv + arow*128 + l4*8;
    #pragma unroll
    for(int ks=0;ks<4;ks++){
      float4 f0=*reinterpret_cast<const float4*>(X+ks*32);
      float4 f1=*reinterpret_cast<const float4*>(X+ks*32+4);
      short8 t;
      t[0]=(short)f2bf(f0.x); t[1]=(short)f2bf(f0.y); t[2]=(short)f2bf(f0.z); t[3]=(short)f2bf(f0.w);
      t[4]=(short)f2bf(f1.x); t[5]=(short)f2bf(f1.y); t[6]=(short)f2bf(f1.z); t[7]=(short)f2bf(f1.w);
      a[ks]=t;
    }
  }else{
    const unsigned short* X=(const unsigned short*)Xv + arow*128 + l4*8;
    #pragma unroll
    for(int ks=0;ks<4;ks++)
      a[ks]=*reinterpret_cast<const short8*>(X+ks*32);
  }
}

// GEMM: weights in registers (loaded once/block); node tiles stream, 2-stage pipeline.
// Row-major outputs: G = bf16(val*dinv), XL = bf16(0.5*val)
template<bool FP32IN>
__launch_bounds__(256, 4)
__global__ void k_gemm(const void* __restrict__ Xv, const unsigned short* __restrict__ Wt,
                       const float* __restrict__ dinv,
                       unsigned short* __restrict__ G, unsigned short* __restrict__ XL, int N){
  int wave=threadIdx.x>>6, lane=threadIdx.x&63;
  int l15=lane&15, l4=lane>>4;
  int blk0=blockIdx.x*128;
  if(blk0>=N) return;
  short8 wf[4][4];
  #pragma unroll
  for(int i=0;i<4;i++){
    int col=(wave*4+i)*16+l15;
    #pragma unroll
    for(int ks=0;ks<4;ks++)
      wf[i][ks]=*reinterpret_cast<const short8*>(Wt+(size_t)col*128+ks*32+l4*8);
  }
  int r0=blk0+l15; if(r0>N-1) r0=N-1;
  short8 aC[4], aN[4];
  load_afrag<FP32IN>(Xv,(size_t)r0,l4,aC);
  #pragma unroll 1
  for(int nt=0;nt<8;nt++){
    int node0=blk0+nt*16;
    if(node0>=N) break;
    if(nt<7){
      int rn=node0+16+l15; if(rn>N-1) rn=N-1;
      load_afrag<FP32IN>(Xv,(size_t)rn,l4,aN);
    }
    f32x4 acc[4];
    #pragma unroll
    for(int i=0;i<4;i++) acc[i]=(f32x4){0.f,0.f,0.f,0.f};
    #pragma unroll
    for(int i=0;i<4;i++){
      #pragma unroll
      for(int ks=0;ks<4;ks++)
        acc[i]=__builtin_amdgcn_mfma_f32_16x16x32_bf16(wf[i][ks],aC[ks],acc[i],0,0,0);
    }
    int node=node0+l15;
    if(node<N){
      if(wave<2){
        float dv=dinv[node];
        #pragma unroll
        for(int i=0;i<4;i++){
          f32x4 v=acc[i];
          uint2 p; p.x=pack2(v[0]*dv,v[1]*dv); p.y=pack2(v[2]*dv,v[3]*dv);
          *reinterpret_cast<uint2*>(G+(size_t)node*128+(wave*4+i)*16+l4*4)=p;
        }
      }else{
        #pragma unroll
        for(int i=0;i<4;i++){
          f32x4 v=acc[i];
          uint2 p; p.x=pack2(v[0]*0.5f,v[1]*0.5f); p.y=pack2(v[2]*0.5f,v[3]*0.5f);
          *reinterpret_cast<uint2*>(XL+(size_t)node*128+((wave-2)*4+i)*16+l4*4)=p;
        }
      }
    }
    #pragma unroll
    for(int ks=0;ks<4;ks++) aC[ks]=aN[ks];
  }
}

// packed f32x2 accumulate: 3 VALU per u32
#define ADDQ(v) do{ \
  unsigned ux=(unsigned)(v).x, uy=(unsigned)(v).y, uz=(unsigned)(v).z, uw=(unsigned)(v).w; \
  accv[0]+=(f32x2){__uint_as_float(ux<<16),__uint_as_float(ux&0xffff0000u)}; \
  accv[1]+=(f32x2){__uint_as_float(uy<<16),__uint_as_float(uy&0xffff0000u)}; \
  accv[2]+=(f32x2){__uint_as_float(uz<<16),__uint_as_float(uz&0xffff0000u)}; \
  accv[3]+=(f32x2){__uint_as_float(uw<<16),__uint_as_float(uw&0xffff0000u)}; \
}while(0)

// conv (standalone, R6-proven @69us): one node per WAVE; 4 lane-groups x 4-deep
// = 16 rows in flight; packed adds; shfl reduce; coalesced 16B H store.
// out = dv2*sum + bh + xlh   (bh pre-halved, XL pre-halved)
template<bool RELU>
__launch_bounds__(256)
__global__ void k_conv(const unsigned short* __restrict__ G, const unsigned short* __restrict__ XL,
                       const float* __restrict__ bh, const float* __restrict__ dinv,
                       const int* __restrict__ csr, const unsigned* __restrict__ meta,
                       unsigned short* __restrict__ H, int N){
  int node=blockIdx.x*4+(threadIdx.x>>6);
  if(node>=N) return;
  int lane=threadIdx.x&63;
  int g=lane>>4, li=lane&15;
  const int4* Gv=(const int4*)G;
  const int4 Z={0,0,0,0};
  f32x2 accv[4];
  #pragma unroll
  for(int i=0;i<4;i++) accv[i]=(f32x2){0.f,0.f};
  if(g==0){
    int4 v=Gv[(size_t)node*16+li];       // self-loop term
    ADDQ(v);
  }
  unsigned mt=meta[node];
  unsigned start=mt&0x1FFFFFu, deg=mt>>21;
  unsigned j=(unsigned)g;
  int4 v0=Z,v1=Z,v2=Z,v3=Z;
  if(j<deg)    v0=Gv[(size_t)csr[start+j]*16+li];
  if(j+4<deg)  v1=Gv[(size_t)csr[start+j+4]*16+li];
  if(j+8<deg)  v2=Gv[(size_t)csr[start+j+8]*16+li];
  if(j+12<deg) v3=Gv[(size_t)csr[start+j+12]*16+li];
  j+=16;
  while(j<deg){
    int4 n0=Gv[(size_t)csr[start+j]*16+li];
    int4 n1=(j+4<deg)?Gv[(size_t)csr[start+j+4]*16+li]:Z;
    int4 n2=(j+8<deg)?Gv[(size_t)csr[start+j+8]*16+li]:Z;
    int4 n3=(j+12<deg)?Gv[(size_t)csr[start+j+12]*16+li]:Z;
    ADDQ(v0); ADDQ(v1); ADDQ(v2); ADDQ(v3);
    v0=n0; v1=n1; v2=n2; v3=n3; j+=16;
  }
  ADDQ(v0); ADDQ(v1); ADDQ(v2); ADDQ(v3);
  float acc[8];
  #pragma unroll
  for(int i=0;i<4;i++){ acc[2*i]=accv[i][0]; acc[2*i+1]=accv[i][1]; }
  #pragma unroll
  for(int i=0;i<8;i++){
    acc[i]+=__shfl_xor(acc[i],16,64);
    acc[i]+=__shfl_xor(acc[i],32,64);
  }
  if(g==0){
    float dv2=0.5f*dinv[node];
    float4 b0=*reinterpret_cast<const float4*>(bh+li*8);
    float4 b1=*reinterpret_cast<const float4*>(bh+li*8+4);
    int4 xv=((const int4*)XL)[(size_t)node*16+li];
    float xl[8];
    { unsigned _x=(unsigned)xv.x,_y=(unsigned)xv.y,_z=(unsigned)xv.z,_w=(unsigned)xv.w;
      xl[0]=bf2f((unsigned short)(_x&0xffffu)); xl[1]=bf2f((unsigned short)(_x>>16));
      xl[2]=bf2f((unsigned short)(_y&0xffffu)); xl[3]=bf2f((unsigned short)(_y>>16));
      xl[4]=bf2f((unsigned short)(_z&0xffffu)); xl[5]=bf2f((unsigned short)(_z>>16));
      xl[6]=bf2f((unsigned short)(_w&0xffffu)); xl[7]=bf2f((unsigned short)(_w>>16)); }
    float bb[8]={b0.x,b0.y,b0.z,b0.w,b1.x,b1.y,b1.z,b1.w};
    float r[8];
    #pragma unroll
    for(int i=0;i<8;i++){
      r[i]=dv2*acc[i]+bb[i]+xl[i];
      if(RELU) r[i]=fmaxf(r[i],0.f);
    }
    int4 o;
    o.x=(int)pack2(r[0],r[1]); o.y=(int)pack2(r[2],r[3]);
    o.z=(int)pack2(r[4],r[5]); o.w=(int)pack2(r[6],r[7]);
    ((int4*)H)[(size_t)node*16+li]=o;
  }
}

// MLP head: relu(H2@Wm1+bm1)@Wm2+bm2 -> injection -> log_softmax -> out
// Epilogue fully wave-parallel: lane(l4,l15) owns classes l4*4..+3 of node l15.
__launch_bounds__(256)
__global__ void k_mlp(const unsigned short* __restrict__ H2,
                      const unsigned short* __restrict__ Wm1t,
                      const unsigned short* __restrict__ Wm2tp,
                      const float* __restrict__ bm1, const float* __restrict__ bm2,
                      const unsigned char* __restrict__ flag, const float* __restrict__ preds,
                      float* __restrict__ out, int N){
  __shared__ __align__(16) unsigned short zt[4][16][136];
  int wave=threadIdx.x>>6, lane=threadIdx.x&63;
  int l15=lane&15, l4=lane>>4;
  int node0=blockIdx.x*64+wave*16;
  int arow=node0+l15; if(arow>N-1) arow=N-1; if(arow<0) arow=0;
  short8 a[4];
  #pragma unroll
  for(int ks=0;ks<4;ks++)
    a[ks]=*reinterpret_cast<const short8*>(H2+(size_t)arow*128+ks*32+l4*8);
  f32x4 acc[8];
  #pragma unroll
  for(int ct=0;ct<8;ct++) acc[ct]=(f32x4){0.f,0.f,0.f,0.f};
  #pragma unroll
  for(int ct=0;ct<8;ct++){
    #pragma unroll
    for(int ks=0;ks<4;ks++){
      short8 bfr=*reinterpret_cast<const short8*>(Wm1t+(size_t)(ct*16+l15)*128+ks*32+l4*8);
      acc[ct]=__builtin_amdgcn_mfma_f32_16x16x32_bf16(bfr,a[ks],acc[ct],0,0,0);
    }
  }
  #pragma unroll
  for(int ct=0;ct<8;ct++){
    float4 bm=*reinterpret_cast<const float4*>(bm1+ct*16+l4*4);
    uint2 p;
    p.x=pack2(fmaxf(acc[ct][0]+bm.x,0.f),fmaxf(acc[ct][1]+bm.y,0.f));
    p.y=pack2(fmaxf(acc[ct][2]+bm.z,0.f),fmaxf(acc[ct][3]+bm.w,0.f));
    *reinterpret_cast<uint2*>(&zt[wave][l15][ct*16+l4*4])=p;
  }
  __syncthreads();
  short8 a2[4];
  #pragma unroll
  for(int ks=0;ks<4;ks++)
    a2[ks]=*reinterpret_cast<const short8*>(&zt[wave][l15][ks*32+l4*8]);
  f32x4 acc2=(f32x4){0.f,0.f,0.f,0.f};
  #pragma unroll
  for(int ks=0;ks<4;ks++){
    short8 bfr=*reinterpret_cast<const short8*>(Wm2tp+(size_t)l15*128+ks*32+l4*8);
    acc2=__builtin_amdgcn_mfma_f32_16x16x32_bf16(bfr,a2[ks],acc2,0,0,0);
  }
  int node=node0+l15;
  bool have=node<N;
  int c0=l4*4;
  float v[4];
  #pragma unroll
  for(int k=0;k<4;k++){
    int c=c0+k;
    v[k]=(c<10)?(acc2[k]+bm2[c]):-3.0e38f;
  }
  if(have && c0<10 && flag[node]){
    #pragma unroll
    for(int k=0;k<4;k++){
      int c=c0+k;
      if(c<10) v[k]+=INJ_LAM*preds[(size_t)node*10+c];
    }
  }
  float m=fmaxf(fmaxf(v[0],v[1]),fmaxf(v[2],v[3]));
  m=fmaxf(m,__shfl_xor(m,16,64));
  m=fmaxf(m,__shfl_xor(m,32,64));
  float s=0.f;
  #pragma unroll
  for(int k=0;k<4;k++){ int c=c0+k; if(c<10) s+=expf(v[k]-m); }
  s+=__shfl_xor(s,16,64);
  s+=__shfl_xor(s,32,64);
  float lse=m+logf(s);
  if(have && c0<10){
    float2 o01; o01.x=v[0]-lse; o01.y=v[1]-lse;
    *reinterpret_cast<float2*>(out+(size_t)node*10+c0)=o01;
    if(c0+2<10){
      float2 o23; o23.x=v[2]-lse; o23.y=v[3]-lse;
      *reinterpret_cast<float2*>(out+(size_t)node*10+c0+2)=o23;
    }
  }
}

extern "C" void kernel_launch(void* const* d_in, const int* in_sizes, int n_in,
                              void* d_out, int out_size, void* d_ws, size_t ws_size,
                              hipStream_t stream){
  const float* x    =(const float*)d_in[0];
  const int*   ei   =(const int*)  d_in[1];
  const int*   inj  =(const int*)  d_in[2];
  const float* preds=(const float*)d_in[3];
  const float* W1 =(const float*)d_in[4];  const float* b1 =(const float*)d_in[5];
  const float* W2 =(const float*)d_in[6];  const float* b2 =(const float*)d_in[7];
  const float* Wl1=(const float*)d_in[8];  const float* Wl2=(const float*)d_in[9];
  const float* Wm1=(const float*)d_in[10]; const float* bm1=(const float*)d_in[11];
  const float* Wm2=(const float*)d_in[12]; const float* bm2=(const float*)d_in[13];
  float* out=(float*)d_out;

  const int N  = in_sizes[0]/128;
  const int E  = in_sizes[1]/2;
  const int NI = in_sizes[2];
  const int* srcp = ei;
  const int* dstp = ei+E;
  const int NBK = (N+BWD-1)>>BSH;   // <=256 for N<=131072

  char* w=(char*)d_ws;
  auto carve=[&](size_t sz)->char*{ char* p=w; w+=(sz+255)&~(size_t)255; return p; };
  unsigned short* S0 =(unsigned short*)carve((size_t)N*128*2); // H1 -> H2; overlay psrc/pdst
  unsigned short* S1 =(unsigned short*)carve((size_t)N*128*2); // G; overlay rank
  unsigned short* S2 =(unsigned short*)carve((size_t)N*128*2); // XL
  unsigned short* Wt1=(unsigned short*)carve(256*128*2);
  unsigned short* Wt2=(unsigned short*)carve(256*128*2);
  unsigned short* Wm1t=(unsigned short*)carve(128*128*2);
  unsigned short* Wm2tp=(unsigned short*)carve(16*128*2);
  float*    dinv  =(float*)   carve((size_t)N*4);
  unsigned* meta  =(unsigned*)carve((size_t)N*4);
  int*      csr   =(int*)     carve((size_t)E*4);
  unsigned char* flags=(unsigned char*)carve(((size_t)N+3)&~(size_t)3);
  unsigned* zcur8 =(unsigned*)carve(256*8*4);
  float* bh1=(float*)carve(128*4);
  float* bh2=(float*)carve(128*4);
  (void)ws_size; (void)n_in; (void)out_size;

  // graph-phase overlays (dead before gemm1/conv1 write S1/S2/S0)
  int* psrc=(int*)S0;
  int* pdst=psrc+(size_t)NBK*BCAP;
  unsigned* rank=(unsigned*)S1;

  const int T=256;
  const int EB=(E+2047)/2048;
  const int nf4=(N+3)/4;
  int gp=(32768>nf4?32768:nf4); gp=(gp+T-1)/T;
  hipLaunchKernelGGL(k_prep, dim3(gp), dim3(T), 0, stream,
                     W1,Wl1,W2,Wl2,Wm1,Wm2,b1,b2,
                     Wt1,Wt2,Wm1t,Wm2tp,bh1,bh2,
                     (unsigned*)flags, nf4, zcur8);
  hipLaunchKernelGGL(k_bscatter, dim3(EB), dim3(T), 0, stream, srcp, dstp, zcur8,
                     psrc, pdst, E);
  hipLaunchKernelGGL(k_bucket, dim3(NBK), dim3(T), 0, stream, psrc, pdst, zcur8, rank,
                     meta, dinv, csr, inj, flags, N, NI, NBK);
  hipLaunchKernelGGL(k_gemm<true>,  dim3((N+127)/128), dim3(T), 0, stream,
                     (const void*)x, Wt1, dinv, S1, S2, N);
  hipLaunchKernelGGL(k_conv<true>,  dim3((N+3)/4), dim3(T), 0, stream,
                     S1, S2, bh1, dinv, csr, meta, S0, N);
  hipLaunchKernelGGL(k_gemm<false>, dim3((N+127)/128), dim3(T), 0, stream,
                     (const void*)S0, Wt2, dinv, S1, S2, N);
  hipLaunchKernelGGL(k_conv<false>, dim3((N+3)/4), dim3(T), 0, stream,
                     S1, S2, bh2, dinv, csr, meta, S0, N);
  hipLaunchKernelGGL(k_mlp, dim3((N+63)/64), dim3(T), 0, stream,
                     S0, Wm1t, Wm2tp, bm1, bm2, flags, preds, out, N);
}

// Round 16
// 307.915 us; speedup vs baseline: 1.0470x; 1.0470x over previous
//
#include <hip/hip_runtime.h>
#include <hip/hip_bf16.h>
#include <math.h>

typedef __attribute__((ext_vector_type(8))) short short8;
typedef __attribute__((ext_vector_type(4))) float f32x4;
typedef __attribute__((ext_vector_type(2))) float f32x2;

#define INJ_LAM 0.8f
#define BSH 9
#define BWD 512     // nodes per bucket
#define BCAP 12288  // padded per-bucket edge capacity (avg 8163 + 45 sigma)

__device__ inline float bf2f(unsigned short s){
  union{unsigned u; float f;} v; v.u=((unsigned)s)<<16; return v.f;
}
__device__ inline unsigned short f2bf(float f){
  __hip_bfloat16 h=__float2bfloat16(f);
  return *reinterpret_cast<unsigned short*>(&h);
}
__device__ inline unsigned pack2(float lo, float hi){
  return ((unsigned)f2bf(hi)<<16)|(unsigned)f2bf(lo);
}

// prep: weight transpose/cast + pre-halved biases + zero flags/zcur
__global__ void k_prep(const float* __restrict__ W1,const float* __restrict__ Wl1,
                       const float* __restrict__ W2,const float* __restrict__ Wl2,
                       const float* __restrict__ Wm1,const float* __restrict__ Wm2,
                       const float* __restrict__ b1,const float* __restrict__ b2,
                       unsigned short* __restrict__ Wt1, unsigned short* __restrict__ Wt2,
                       unsigned short* __restrict__ Wm1t, unsigned short* __restrict__ Wm2tp,
                       float* __restrict__ bh1, float* __restrict__ bh2,
                       unsigned* __restrict__ flags32, int nf4,
                       unsigned* __restrict__ zcur8){
  int i=blockIdx.x*blockDim.x+threadIdx.x;
  if(i<256*128){
    int c=i>>7, k=i&127;
    float v1=(c<128)?W1[k*128+c]:Wl1[k*128+(c-128)];
    float v2=(c<128)?W2[k*128+c]:Wl2[k*128+(c-128)];
    Wt1[i]=f2bf(v1); Wt2[i]=f2bf(v2);
    if(c<128) Wm1t[i]=f2bf(Wm1[k*128+c]);
    if(c<16)  Wm2tp[i]=f2bf((c<10)?Wm2[k*10+c]:0.f);
    if(i<128){ bh1[i]=0.5f*b1[i]; bh2[i]=0.5f*b2[i]; }
  }
  if(i<nf4) flags32[i]=0u;
  if(i<2048) zcur8[i]=0u;
}

// bscatter: group edges by bucket into PADDED per-bucket arrays (b*BCAP).
// LDS local rank + one global atomic per nonzero bucket per block. No bhist pass.
__launch_bounds__(256)
__global__ void k_bscatter(const int* __restrict__ src, const int* __restrict__ dst,
                           unsigned* __restrict__ zcur8,
                           int* __restrict__ psrc, int* __restrict__ pdst, int E){
  __shared__ unsigned lh[256];
  __shared__ unsigned gb[256];
  int t=threadIdx.x;
  lh[t]=0u; __syncthreads();
  int base=blockIdx.x*2048;
  unsigned lr[8]; int bk[8], sv[8], dv_[8];
  #pragma unroll
  for(int k=0;k<8;k++){
    int e=base+k*256+t;
    if(e<E){
      int d=dst[e]; int b=d>>BSH;
      bk[k]=b; dv_[k]=d; sv[k]=src[e];
      lr[k]=atomicAdd(&lh[b],1u);
    } else bk[k]=-1;
  }
  __syncthreads();
  if(lh[t]) gb[t]=atomicAdd(&zcur8[t*8],lh[t]);
  __syncthreads();
  #pragma unroll
  for(int k=0;k<8;k++){
    if(bk[k]>=0){
      unsigned p=(unsigned)bk[k]*BCAP+gb[bk[k]]+lr[k];
      psrc[p]=sv[k]; pdst[p]=dv_[k];
    }
  }
}

// bucket: derive global csr bases by prefix over final zcur8 counts; exact
// per-node cnt+rank via LDS atomics; LDS scan -> offs; write csr compactly.
// meta[node] = csr_start | (deg<<21). Also marks inject flags.
__launch_bounds__(256)
__global__ void k_bucket(const int* __restrict__ psrc, const int* __restrict__ pdst,
                         const unsigned* __restrict__ zcur8, unsigned* __restrict__ rank,
                         unsigned* __restrict__ meta, float* __restrict__ dinv,
                         int* __restrict__ csr,
                         const int* __restrict__ inj, unsigned char* __restrict__ flag,
                         int N, int NI, int NBK){
  __shared__ unsigned lc[BWD];
  __shared__ unsigned lo[BWD];
  __shared__ unsigned ss[256];
  int b=blockIdx.x, t=threadIdx.x;
  for(int i=b*256+t;i<NI;i+=gridDim.x*256) flag[inj[i]]=1;
  unsigned v=(t<NBK)?zcur8[t*8]:0u;
  ss[t]=v; lc[t]=0u; lc[t+256]=0u;
  __syncthreads();
  for(int off=1;off<256;off<<=1){
    unsigned u=(t>=off)?ss[t-off]:0u; __syncthreads();
    ss[t]+=u; __syncthreads();
  }
  unsigned cnt_b=zcur8[b*8];
  unsigned e1=ss[b];
  unsigned e0=e1-cnt_b;
  __syncthreads();
  int lo_node=b<<BSH;
  unsigned pbase=(unsigned)b*BCAP;
  for(unsigned i=t;i<cnt_b;i+=256){
    int dl=pdst[pbase+i]-lo_node;
    rank[pbase+i]=atomicAdd(&lc[dl],1u);
  }
  __syncthreads();
  unsigned c0=lc[2*t], c1=lc[2*t+1], ps=c0+c1;
  ss[t]=ps; __syncthreads();
  for(int off=1;off<256;off<<=1){
    unsigned u=(t>=off)?ss[t-off]:0u; __syncthreads();
    ss[t]+=u; __syncthreads();
  }
  unsigned excl=ss[t]-ps;
  lo[2*t]=excl; lo[2*t+1]=excl+c0;
  __syncthreads();
  #pragma unroll
  for(int k=0;k<2;k++){
    int nl=t+k*256; int node=lo_node+nl;
    if(node<N){
      unsigned c=lc[nl];
      meta[node]=(e0+lo[nl])|(c<<21);
      dinv[node]=rsqrtf((float)(c+1u));
    }
  }
  for(unsigned i=t;i<cnt_b;i+=256){
    int dl=pdst[pbase+i]-lo_node;
    csr[e0+lo[dl]+rank[pbase+i]]=psrc[pbase+i];
  }
}

template<bool FP32IN>
__device__ inline void load_afrag(const void* __restrict__ Xv, size_t arow, int l4, short8* a){
  if(FP32IN){
    const float* X=(const float*)Xv + arow*128 + l4*8;
    #pragma unroll
    for(int ks=0;ks<4;ks++){
      float4 f0=*reinterpret_cast<const float4*>(X+ks*32);
      float4 f1=*reinterpret_cast<const float4*>(X+ks*32+4);
      short8 t;
      t[0]=(short)f2bf(f0.x); t[1]=(short)f2bf(f0.y); t[2]=(short)f2bf(f0.z); t[3]=(short)f2bf(f0.w);
      t[4]=(short)f2bf(f1.x); t[5]=(short)f2bf(f1.y); t[6]=(short)f2bf(f1.z); t[7]=(short)f2bf(f1.w);
      a[ks]=t;
    }
  }else{
    const unsigned short* X=(const unsigned short*)Xv + arow*128 + l4*8;
    #pragma unroll
    for(int ks=0;ks<4;ks++)
      a[ks]=*reinterpret_cast<const short8*>(X+ks*32);
  }
}

// GEMM1: weights in registers (loaded once/block); node tiles stream, 2-stage pipeline.
// Row-major outputs: G = bf16(val*dinv), XL = bf16(0.5*val)
template<bool FP32IN>
__launch_bounds__(256, 4)
__global__ void k_gemm(const void* __restrict__ Xv, const unsigned short* __restrict__ Wt,
                       const float* __restrict__ dinv,
                       unsigned short* __restrict__ G, unsigned short* __restrict__ XL, int N){
  int wave=threadIdx.x>>6, lane=threadIdx.x&63;
  int l15=lane&15, l4=lane>>4;
  int blk0=blockIdx.x*128;
  if(blk0>=N) return;
  short8 wf[4][4];
  #pragma unroll
  for(int i=0;i<4;i++){
    int col=(wave*4+i)*16+l15;
    #pragma unroll
    for(int ks=0;ks<4;ks++)
      wf[i][ks]=*reinterpret_cast<const short8*>(Wt+(size_t)col*128+ks*32+l4*8);
  }
  int r0=blk0+l15; if(r0>N-1) r0=N-1;
  short8 aC[4], aN[4];
  load_afrag<FP32IN>(Xv,(size_t)r0,l4,aC);
  #pragma unroll 1
  for(int nt=0;nt<8;nt++){
    int node0=blk0+nt*16;
    if(node0>=N) break;
    if(nt<7){
      int rn=node0+16+l15; if(rn>N-1) rn=N-1;
      load_afrag<FP32IN>(Xv,(size_t)rn,l4,aN);
    }
    f32x4 acc[4];
    #pragma unroll
    for(int i=0;i<4;i++) acc[i]=(f32x4){0.f,0.f,0.f,0.f};
    #pragma unroll
    for(int i=0;i<4;i++){
      #pragma unroll
      for(int ks=0;ks<4;ks++)
        acc[i]=__builtin_amdgcn_mfma_f32_16x16x32_bf16(wf[i][ks],aC[ks],acc[i],0,0,0);
    }
    int node=node0+l15;
    if(node<N){
      if(wave<2){
        float dv=dinv[node];
        #pragma unroll
        for(int i=0;i<4;i++){
          f32x4 v=acc[i];
          uint2 p; p.x=pack2(v[0]*dv,v[1]*dv); p.y=pack2(v[2]*dv,v[3]*dv);
          *reinterpret_cast<uint2*>(G+(size_t)node*128+(wave*4+i)*16+l4*4)=p;
        }
      }else{
        #pragma unroll
        for(int i=0;i<4;i++){
          f32x4 v=acc[i];
          uint2 p; p.x=pack2(v[0]*0.5f,v[1]*0.5f); p.y=pack2(v[2]*0.5f,v[3]*0.5f);
          *reinterpret_cast<uint2*>(XL+(size_t)node*128+((wave-2)*4+i)*16+l4*4)=p;
        }
      }
    }
    #pragma unroll
    for(int ks=0;ks<4;ks++) aC[ks]=aN[ks];
  }
}

// packed f32x2 accumulate: 3 VALU per u32
#define ADDQ(v) do{ \
  unsigned ux=(unsigned)(v).x, uy=(unsigned)(v).y, uz=(unsigned)(v).z, uw=(unsigned)(v).w; \
  accv[0]+=(f32x2){__uint_as_float(ux<<16),__uint_as_float(ux&0xffff0000u)}; \
  accv[1]+=(f32x2){__uint_as_float(uy<<16),__uint_as_float(uy&0xffff0000u)}; \
  accv[2]+=(f32x2){__uint_as_float(uz<<16),__uint_as_float(uz&0xffff0000u)}; \
  accv[3]+=(f32x2){__uint_as_float(uw<<16),__uint_as_float(uw&0xffff0000u)}; \
}while(0)

// conv for ONE node per 16-lane GROUP: each lane owns a 16B column chunk,
// 4-deep row pipeline (32 VGPRs of pipeline -> no spill), no cross-lane reduce.
// Result row -> LDS (bf16). out = dv2*sum + bh + xlh (bh pre-halved, XL pre-halved)
template<bool RELU>
__device__ __forceinline__ void conv_group(int node, int N,
    const unsigned short* __restrict__ G, const unsigned short* __restrict__ XL,
    const float* __restrict__ bh, const float* __restrict__ dinv,
    const int* __restrict__ csr, const unsigned* __restrict__ meta,
    unsigned short* __restrict__ ldsrow, int li){
  if(node>=N) return;
  const int4* Gv=(const int4*)G;
  const int4 Z={0,0,0,0};
  f32x2 accv[4];
  #pragma unroll
  for(int i=0;i<4;i++) accv[i]=(f32x2){0.f,0.f};
  { int4 v=Gv[(size_t)node*16+li]; ADDQ(v); }   // self-loop
  unsigned mt=meta[node];
  unsigned start=mt&0x1FFFFFu, deg=mt>>21;
  int4 v0=Z,v1=Z,v2=Z,v3=Z;
  if(0u<deg) v0=Gv[(size_t)csr[start  ]*16+li];
  if(1u<deg) v1=Gv[(size_t)csr[start+1]*16+li];
  if(2u<deg) v2=Gv[(size_t)csr[start+2]*16+li];
  if(3u<deg) v3=Gv[(size_t)csr[start+3]*16+li];
  unsigned j=4;
  while(j<deg){
    int4 n0=Gv[(size_t)csr[start+j]*16+li];
    int4 n1=(j+1<deg)?Gv[(size_t)csr[start+j+1]*16+li]:Z;
    int4 n2=(j+2<deg)?Gv[(size_t)csr[start+j+2]*16+li]:Z;
    int4 n3=(j+3<deg)?Gv[(size_t)csr[start+j+3]*16+li]:Z;
    ADDQ(v0); ADDQ(v1); ADDQ(v2); ADDQ(v3);
    v0=n0; v1=n1; v2=n2; v3=n3; j+=4;
  }
  ADDQ(v0); ADDQ(v1); ADDQ(v2); ADDQ(v3);
  float acc[8];
  #pragma unroll
  for(int i=0;i<4;i++){ acc[2*i]=accv[i][0]; acc[2*i+1]=accv[i][1]; }
  float dv2=0.5f*dinv[node];
  float4 b0=*reinterpret_cast<const float4*>(bh+li*8);
  float4 b1=*reinterpret_cast<const float4*>(bh+li*8+4);
  int4 xv=((const int4*)XL)[(size_t)node*16+li];
  float xl[8];
  { unsigned _x=(unsigned)xv.x,_y=(unsigned)xv.y,_z=(unsigned)xv.z,_w=(unsigned)xv.w;
    xl[0]=bf2f((unsigned short)(_x&0xffffu)); xl[1]=bf2f((unsigned short)(_x>>16));
    xl[2]=bf2f((unsigned short)(_y&0xffffu)); xl[3]=bf2f((unsigned short)(_y>>16));
    xl[4]=bf2f((unsigned short)(_z&0xffffu)); xl[5]=bf2f((unsigned short)(_z>>16));
    xl[6]=bf2f((unsigned short)(_w&0xffffu)); xl[7]=bf2f((unsigned short)(_w>>16)); }
  float bb[8]={b0.x,b0.y,b0.z,b0.w,b1.x,b1.y,b1.z,b1.w};
  float r[8];
  #pragma unroll
  for(int i=0;i<8;i++){
    r[i]=dv2*acc[i]+bb[i]+xl[i];
    if(RELU) r[i]=fmaxf(r[i],0.f);
  }
  int4 o;
  o.x=(int)pack2(r[0],r[1]); o.y=(int)pack2(r[2],r[3]);
  o.z=(int)pack2(r[4],r[5]); o.w=(int)pack2(r[6],r[7]);
  *reinterpret_cast<int4*>(ldsrow+li*8)=o;
}

// fused conv1 + gemm2: block = 4 waves / 16 nodes, one node per 16-lane group.
// Phase2: 16 col-tiles of Wt2 (4/wave), weights from L2 post-barrier.
// G2 overlays XL1 (own rows only).
__launch_bounds__(256, 6)
__global__ void k_convg(const unsigned short* __restrict__ G1, const unsigned short* __restrict__ XL1,
                        const float* __restrict__ bh1, const float* __restrict__ dinv,
                        const int* __restrict__ csr, const unsigned* __restrict__ meta,
                        const unsigned short* __restrict__ Wt2,
                        unsigned short* __restrict__ G2, unsigned short* __restrict__ XL2, int N){
  __shared__ __align__(16) unsigned short ht[16][136];
  int wave=threadIdx.x>>6, lane=threadIdx.x&63;
  int l15=lane&15, l4=lane>>4;
  int blk0=blockIdx.x*16;
  int nl=wave*4+l4;                      // group index 0..15 = node slot
  conv_group<true>(blk0+nl, N, G1, XL1, bh1, dinv, csr, meta, &ht[nl][0], l15);
  __syncthreads();
  short8 a[4];
  #pragma unroll
  for(int ks=0;ks<4;ks++)
    a[ks]=*reinterpret_cast<const short8*>(&ht[l15][ks*32+l4*8]);
  int node=blk0+l15;
  float dv=(node<N)?dinv[node]:0.f;
  #pragma unroll
  for(int i=0;i<4;i++){
    int ct=wave*4+i;
    short8 wfr[4];
    #pragma unroll
    for(int ks=0;ks<4;ks++)
      wfr[ks]=*reinterpret_cast<const short8*>(Wt2+(size_t)(ct*16+l15)*128+ks*32+l4*8);
    f32x4 acc=(f32x4){0.f,0.f,0.f,0.f};
    #pragma unroll
    for(int ks=0;ks<4;ks++)
      acc=__builtin_amdgcn_mfma_f32_16x16x32_bf16(wfr[ks],a[ks],acc,0,0,0);
    if(node<N){
      if(ct<8){
        uint2 p; p.x=pack2(acc[0]*dv,acc[1]*dv); p.y=pack2(acc[2]*dv,acc[3]*dv);
        *reinterpret_cast<uint2*>(G2+(size_t)node*128+ct*16+l4*4)=p;
      }else{
        uint2 p; p.x=pack2(acc[0]*0.5f,acc[1]*0.5f); p.y=pack2(acc[2]*0.5f,acc[3]*0.5f);
        *reinterpret_cast<uint2*>(XL2+(size_t)node*128+(ct-8)*16+l4*4)=p;
      }
    }
  }
}

// fused conv2 + MLP head: block = 4 waves / 16 nodes.
// Phase2: Wm1 (8 ct, 2/wave) -> zt. Phase3: wave 0: Wm2 + injection + log_softmax.
__launch_bounds__(256, 6)
__global__ void k_convm(const unsigned short* __restrict__ G2, const unsigned short* __restrict__ XL2,
                        const float* __restrict__ bh2, const float* __restrict__ dinv,
                        const int* __restrict__ csr, const unsigned* __restrict__ meta,
                        const unsigned short* __restrict__ Wm1t, const unsigned short* __restrict__ Wm2tp,
                        const float* __restrict__ bm1, const float* __restrict__ bm2,
                        const unsigned char* __restrict__ flag, const float* __restrict__ preds,
                        float* __restrict__ out, int N){
  __shared__ __align__(16) unsigned short ht[16][136];
  __shared__ __align__(16) unsigned short zt[16][136];
  int wave=threadIdx.x>>6, lane=threadIdx.x&63;
  int l15=lane&15, l4=lane>>4;
  int blk0=blockIdx.x*16;
  int nl=wave*4+l4;
  conv_group<false>(blk0+nl, N, G2, XL2, bh2, dinv, csr, meta, &ht[nl][0], l15);
  __syncthreads();
  short8 a[4];
  #pragma unroll
  for(int ks=0;ks<4;ks++)
    a[ks]=*reinterpret_cast<const short8*>(&ht[l15][ks*32+l4*8]);
  #pragma unroll
  for(int i=0;i<2;i++){
    int ct=wave*2+i;
    short8 wfr[4];
    #pragma unroll
    for(int ks=0;ks<4;ks++)
      wfr[ks]=*reinterpret_cast<const short8*>(Wm1t+(size_t)(ct*16+l15)*128+ks*32+l4*8);
    f32x4 acc=(f32x4){0.f,0.f,0.f,0.f};
    #pragma unroll
    for(int ks=0;ks<4;ks++)
      acc=__builtin_amdgcn_mfma_f32_16x16x32_bf16(wfr[ks],a[ks],acc,0,0,0);
    float4 bm=*reinterpret_cast<const float4*>(bm1+ct*16+l4*4);
    uint2 p;
    p.x=pack2(fmaxf(acc[0]+bm.x,0.f),fmaxf(acc[1]+bm.y,0.f));
    p.y=pack2(fmaxf(acc[2]+bm.z,0.f),fmaxf(acc[3]+bm.w,0.f));
    *reinterpret_cast<uint2*>(&zt[l15][ct*16+l4*4])=p;
  }
  __syncthreads();
  if(wave==0){
    short8 a2[4], w2[4];
    #pragma unroll
    for(int ks=0;ks<4;ks++){
      a2[ks]=*reinterpret_cast<const short8*>(&zt[l15][ks*32+l4*8]);
      w2[ks]=*reinterpret_cast<const short8*>(Wm2tp+(size_t)l15*128+ks*32+l4*8);
    }
    f32x4 acc2=(f32x4){0.f,0.f,0.f,0.f};
    #pragma unroll
    for(int ks=0;ks<4;ks++)
      acc2=__builtin_amdgcn_mfma_f32_16x16x32_bf16(w2[ks],a2[ks],acc2,0,0,0);
    int node=blk0+l15;
    bool have=node<N;
    int c0=l4*4;
    float v[4];
    #pragma unroll
    for(int k=0;k<4;k++){
      int c=c0+k;
      v[k]=(c<10)?(acc2[k]+bm2[c]):-3.0e38f;
    }
    if(have && c0<10 && flag[node]){
      #pragma unroll
      for(int k=0;k<4;k++){
        int c=c0+k;
        if(c<10) v[k]+=INJ_LAM*preds[(size_t)node*10+c];
      }
    }
    float m=fmaxf(fmaxf(v[0],v[1]),fmaxf(v[2],v[3]));
    m=fmaxf(m,__shfl_xor(m,16,64));
    m=fmaxf(m,__shfl_xor(m,32,64));
    float s=0.f;
    #pragma unroll
    for(int k=0;k<4;k++){ int c=c0+k; if(c<10) s+=expf(v[k]-m); }
    s+=__shfl_xor(s,16,64);
    s+=__shfl_xor(s,32,64);
    float lse=m+logf(s);
    if(have && c0<10){
      float2 o01; o01.x=v[0]-lse; o01.y=v[1]-lse;
      *reinterpret_cast<float2*>(out+(size_t)node*10+c0)=o01;
      if(c0+2<10){
        float2 o23; o23.x=v[2]-lse; o23.y=v[3]-lse;
        *reinterpret_cast<float2*>(out+(size_t)node*10+c0+2)=o23;
      }
    }
  }
}

extern "C" void kernel_launch(void* const* d_in, const int* in_sizes, int n_in,
                              void* d_out, int out_size, void* d_ws, size_t ws_size,
                              hipStream_t stream){
  const float* x    =(const float*)d_in[0];
  const int*   ei   =(const int*)  d_in[1];
  const int*   inj  =(const int*)  d_in[2];
  const float* preds=(const float*)d_in[3];
  const float* W1 =(const float*)d_in[4];  const float* b1 =(const float*)d_in[5];
  const float* W2 =(const float*)d_in[6];  const float* b2 =(const float*)d_in[7];
  const float* Wl1=(const float*)d_in[8];  const float* Wl2=(const float*)d_in[9];
  const float* Wm1=(const float*)d_in[10]; const float* bm1=(const float*)d_in[11];
  const float* Wm2=(const float*)d_in[12]; const float* bm2=(const float*)d_in[13];
  float* out=(float*)d_out;

  const int N  = in_sizes[0]/128;
  const int E  = in_sizes[1]/2;
  const int NI = in_sizes[2];
  const int* srcp = ei;
  const int* dstp = ei+E;
  const int NBK = (N+BWD-1)>>BSH;   // <=256 for N<=131072

  char* w=(char*)d_ws;
  auto carve=[&](size_t sz)->char*{ char* p=w; w+=(sz+255)&~(size_t)255; return p; };
  unsigned short* S1 =(unsigned short*)carve((size_t)N*128*2); // G1; overlay rank (padded)
  unsigned short* S2 =(unsigned short*)carve((size_t)N*128*2); // XL1 -> G2 (own-row overlay)
  unsigned short* S3 =(unsigned short*)carve((size_t)N*128*2); // XL2; overlay padded psrc/pdst
  unsigned short* Wt1=(unsigned short*)carve(256*128*2);
  unsigned short* Wt2=(unsigned short*)carve(256*128*2);
  unsigned short* Wm1t=(unsigned short*)carve(128*128*2);
  unsigned short* Wm2tp=(unsigned short*)carve(16*128*2);
  float*    dinv  =(float*)   carve((size_t)N*4);
  unsigned* meta  =(unsigned*)carve((size_t)N*4);
  int*      csr   =(int*)     carve((size_t)E*4);
  unsigned char* flags=(unsigned char*)carve(((size_t)N+3)&~(size_t)3);
  unsigned* zcur8 =(unsigned*)carve(256*8*4);
  float* bh1=(float*)carve(128*4);
  float* bh2=(float*)carve(128*4);
  (void)ws_size; (void)n_in; (void)out_size;

  // graph-phase overlays (dead before gemm1/convg write S1/S3)
  int* psrc=(int*)S3;
  int* pdst=psrc+(size_t)NBK*BCAP;
  unsigned* rank=(unsigned*)S1;

  const int T=256;
  const int EB=(E+2047)/2048;
  const int nf4=(N+3)/4;
  int gp=(32768>nf4?32768:nf4); gp=(gp+T-1)/T;
  hipLaunchKernelGGL(k_prep, dim3(gp), dim3(T), 0, stream,
                     W1,Wl1,W2,Wl2,Wm1,Wm2,b1,b2,
                     Wt1,Wt2,Wm1t,Wm2tp,bh1,bh2,
                     (unsigned*)flags, nf4, zcur8);
  hipLaunchKernelGGL(k_bscatter, dim3(EB), dim3(T), 0, stream, srcp, dstp, zcur8,
                     psrc, pdst, E);
  hipLaunchKernelGGL(k_bucket, dim3(NBK), dim3(T), 0, stream, psrc, pdst, zcur8, rank,
                     meta, dinv, csr, inj, flags, N, NI, NBK);
  hipLaunchKernelGGL(k_gemm<true>, dim3((N+127)/128), dim3(T), 0, stream,
                     (const void*)x, Wt1, dinv, S1, S2, N);
  hipLaunchKernelGGL(k_convg, dim3((N+15)/16), dim3(T), 0, stream,
                     S1, S2, bh1, dinv, csr, meta, Wt2, S2, S3, N);
  hipLaunchKernelGGL(k_convm, dim3((N+15)/16), dim3(T), 0, stream,
                     S2, S3, bh2, dinv, csr, meta, Wm1t, Wm2tp, bm1, bm2,
                     flags, preds, out, N);
}